// Round 1
// baseline (73.619 us; speedup 1.0000x reference)
//
#include <hip/hip_runtime.h>
#include <hip/hip_bf16.h>

typedef __attribute__((ext_vector_type(8))) short short8;
typedef __attribute__((ext_vector_type(4))) float f32x4;
typedef __attribute__((ext_vector_type(4))) unsigned short ushort4v;
typedef unsigned short u16;

#define MFMA16(a, b, c) __builtin_amdgcn_mfma_f32_16x16x32_bf16((a), (b), (c), 0, 0, 0)

__device__ __forceinline__ u16 f2bf(float f) {
    union { float f; unsigned int u; } v; v.f = f;
    unsigned int r = v.u + 0x7FFFu + ((v.u >> 16) & 1u);   // RNE to bf16
    return (u16)(r >> 16);
}

// One workgroup per batch. 8 waves, wave w owns query rows [32w, 32w+32).
__global__ __launch_bounds__(512, 2)
void attn_head_fused(const float* __restrict__ x,
                     const float* __restrict__ Wq,
                     const float* __restrict__ Wk,
                     const float* __restrict__ Wv,
                     const float* __restrict__ dmask,
                     float* __restrict__ out)
{
    // padded LDS: strides chosen so 16-lane row-strided access spreads >=8 banks
    __shared__ u16 lq[256][72];      // q  [t][h]   36864 B
    __shared__ u16 lk[256][72];      // k  [s][h]   36864 B
    __shared__ u16 lvT[64][264];     // v^T [h][s]  33792 B
    __shared__ union {
        u16 wt[64][264];             // W^T [n][c]  33792 B (projection phase)
        u16 pb[8][32][40];           // per-wave P^T [s_loc][t_loc] (attention phase)
    } sm;

    const int b   = blockIdx.x;
    const int tid = threadIdx.x;
    const int w   = tid >> 6;   // wave 0..7
    const int l   = tid & 63;
    const int lr  = l & 15;     // lane "16-dim" part
    const int lg  = l >> 4;     // lane group 0..3

    const float* xb = x + (size_t)b * (256 * 256);

    // ---- Phase 0: x A-fragments for rows 32w..32w+31, all K=256 (kept in regs, reused 3x) ----
    // A-frag layout (16x16x32): row = lr, k = ks*32 + lg*8 + [0..7]
    short8 af[2][8];
    #pragma unroll
    for (int ti = 0; ti < 2; ++ti) {
        const float* xr = xb + (size_t)(32 * w + 16 * ti + lr) * 256 + lg * 8;
        #pragma unroll
        for (int ks = 0; ks < 8; ++ks) {
            f32x4 a0 = *(const f32x4*)(xr + ks * 32);
            f32x4 a1 = *(const f32x4*)(xr + ks * 32 + 4);
            short8 f;
            f[0] = (short)f2bf(a0[0]); f[1] = (short)f2bf(a0[1]);
            f[2] = (short)f2bf(a0[2]); f[3] = (short)f2bf(a0[3]);
            f[4] = (short)f2bf(a1[0]); f[5] = (short)f2bf(a1[1]);
            f[6] = (short)f2bf(a1[2]); f[7] = (short)f2bf(a1[3]);
            af[ti][ks] = f;
        }
    }

    // ---- Phase 1: projections q, k, v ----
    const float* Ws[3] = {Wq, Wk, Wv};
    #pragma unroll
    for (int m = 0; m < 3; ++m) {
        // stage W^T (bf16) into sm.wt : wt[n][c] = W[c][n]
        const float* Wm = Ws[m];
        #pragma unroll
        for (int i = 0; i < 32; ++i) {
            int e = tid + i * 512;              // 0..16383, coalesced global read
            sm.wt[e & 63][e >> 6] = f2bf(Wm[e]);
        }
        __syncthreads();

        f32x4 acc[2][4];
        #pragma unroll
        for (int ti = 0; ti < 2; ++ti)
            #pragma unroll
            for (int nj = 0; nj < 4; ++nj)
                acc[ti][nj] = (f32x4){0.f, 0.f, 0.f, 0.f};

        #pragma unroll
        for (int ks = 0; ks < 8; ++ks) {
            #pragma unroll
            for (int nj = 0; nj < 4; ++nj) {
                // B-frag: col n = 16nj+lr, k = ks*32 + lg*8 + [0..7]
                short8 bf = *(const short8*)&sm.wt[16 * nj + lr][ks * 32 + lg * 8];
                #pragma unroll
                for (int ti = 0; ti < 2; ++ti)
                    acc[ti][nj] = MFMA16(af[ti][ks], bf, acc[ti][nj]);
            }
        }

        // C/D layout: col = lr, row = lg*4 + j  (within 16x16 tile)
        if (m == 0 || m == 1) {
            u16 (*dst)[72] = (m == 0) ? lq : lk;
            #pragma unroll
            for (int ti = 0; ti < 2; ++ti) {
                #pragma unroll
                for (int nj = 0; nj < 4; ++nj) {
                    const int t0 = 32 * w + 16 * ti + 4 * lg;
                    const int n  = 16 * nj + lr;
                    #pragma unroll
                    for (int j = 0; j < 4; ++j)
                        dst[t0 + j][n] = f2bf(acc[ti][nj][j]);
                }
            }
        } else {
            // v stored transposed: lvT[h][s]; 4 consecutive s pack to one b64 write
            #pragma unroll
            for (int ti = 0; ti < 2; ++ti) {
                #pragma unroll
                for (int nj = 0; nj < 4; ++nj) {
                    const int s0 = 32 * w + 16 * ti + 4 * lg;
                    const int n  = 16 * nj + lr;
                    ushort4v pk;
                    pk[0] = f2bf(acc[ti][nj][0]);
                    pk[1] = f2bf(acc[ti][nj][1]);
                    pk[2] = f2bf(acc[ti][nj][2]);
                    pk[3] = f2bf(acc[ti][nj][3]);
                    *(ushort4v*)&lvT[n][s0] = pk;
                }
            }
        }
        __syncthreads();
    }

    // ---- Phase 2: attention for rows 32w..32w+31 ----
    // q A-frags (reused across all s-tiles)
    short8 qf[2][2];
    #pragma unroll
    for (int ti = 0; ti < 2; ++ti)
        #pragma unroll
        for (int ks = 0; ks < 2; ++ks)
            qf[ti][ks] = *(const short8*)&lq[32 * w + 16 * ti + lr][ks * 32 + lg * 8];

    const int nst = 2 * w + 2;    // causal: s-tiles 0..nst-1 touch this wave's rows
    f32x4 S[16][2];               // [stile][ti] — statically indexed (full unroll)

    #pragma unroll
    for (int st = 0; st < 16; ++st) {
        if (st < nst) {
            short8 kf0 = *(const short8*)&lk[16 * st + lr][lg * 8];
            short8 kf1 = *(const short8*)&lk[16 * st + lr][32 + lg * 8];
            #pragma unroll
            for (int ti = 0; ti < 2; ++ti) {
                f32x4 a = (f32x4){0.f, 0.f, 0.f, 0.f};
                a = MFMA16(qf[ti][0], kf0, a);
                a = MFMA16(qf[ti][1], kf1, a);
                S[st][ti] = a;
            }
        }
    }

    // softmax: scale+causal-mask, row max, exp, row sum (rows indexed by (ti,j); s by (st,lr))
    float mx[2][4], sum[2][4], rs[2][4];
    #pragma unroll
    for (int ti = 0; ti < 2; ++ti)
        #pragma unroll
        for (int j = 0; j < 4; ++j) { mx[ti][j] = -1e30f; sum[ti][j] = 0.f; }

    #pragma unroll
    for (int st = 0; st < 16; ++st) {
        if (st < nst) {
            const int s = 16 * st + lr;
            #pragma unroll
            for (int ti = 0; ti < 2; ++ti) {
                const int tb = 32 * w + 16 * ti + 4 * lg;
                #pragma unroll
                for (int j = 0; j < 4; ++j) {
                    float Lv = (s <= tb + j) ? S[st][ti][j] * 0.125f : -1e30f;
                    S[st][ti][j] = Lv;
                    mx[ti][j] = fmaxf(mx[ti][j], Lv);
                }
            }
        }
    }
    #pragma unroll
    for (int d = 1; d < 16; d <<= 1)
        #pragma unroll
        for (int ti = 0; ti < 2; ++ti)
            #pragma unroll
            for (int j = 0; j < 4; ++j)
                mx[ti][j] = fmaxf(mx[ti][j], __shfl_xor(mx[ti][j], d, 64));

    #pragma unroll
    for (int st = 0; st < 16; ++st) {
        if (st < nst) {
            #pragma unroll
            for (int ti = 0; ti < 2; ++ti)
                #pragma unroll
                for (int j = 0; j < 4; ++j) {
                    float p = exp2f((S[st][ti][j] - mx[ti][j]) * 1.44269504f);
                    S[st][ti][j] = p;
                    sum[ti][j] += p;
                }
        }
    }
    #pragma unroll
    for (int d = 1; d < 16; d <<= 1)
        #pragma unroll
        for (int ti = 0; ti < 2; ++ti)
            #pragma unroll
            for (int j = 0; j < 4; ++j)
                sum[ti][j] += __shfl_xor(sum[ti][j], d, 64);
    #pragma unroll
    for (int ti = 0; ti < 2; ++ti)
        #pragma unroll
        for (int j = 0; j < 4; ++j)
            rs[ti][j] = 1.33333333333f / sum[ti][j];   // 1/sum * 1/(1-0.25)

    // ---- PV: out^T = v^T @ P^T, K-chunks of 32 s ----
    f32x4 O[4][2];   // [h-tile][t-tile]
    #pragma unroll
    for (int ht = 0; ht < 4; ++ht)
        #pragma unroll
        for (int tt = 0; tt < 2; ++tt)
            O[ht][tt] = (f32x4){0.f, 0.f, 0.f, 0.f};

    const float* mb = dmask + (size_t)b * (256 * 256);
    const int nchunk = w + 1;
    #pragma unroll
    for (int sk = 0; sk < 8; ++sk) {
        if (sk < nchunk) {
            // P (softmax * dropout) -> bf16 -> wave-private P^T buffer
            #pragma unroll
            for (int sl = 0; sl < 2; ++sl) {
                const int st = 2 * sk + sl;
                const int s  = 16 * st + lr;
                #pragma unroll
                for (int ti = 0; ti < 2; ++ti) {
                    const int tb = 32 * w + 16 * ti + 4 * lg;
                    ushort4v pk;
                    #pragma unroll
                    for (int j = 0; j < 4; ++j) {
                        float mk = mb[(size_t)(tb + j) * 256 + s];
                        float p  = (mk >= 0.25f) ? S[st][ti][j] * rs[ti][j] : 0.f;
                        pk[j] = f2bf(p);
                    }
                    // pb[s_loc][t_loc], 4 consecutive t packed
                    *(ushort4v*)&sm.pb[w][16 * sl + lr][16 * ti + 4 * lg] = pk;
                }
            }
            asm volatile("s_waitcnt lgkmcnt(0)" ::: "memory");  // cross-lane write->read
            // B-frags of P^T: col t_loc = 16tt+lr, k s_loc = lg*8 + i
            short8 pf[2];
            #pragma unroll
            for (int tt = 0; tt < 2; ++tt) {
                short8 f;
                #pragma unroll
                for (int i = 0; i < 8; ++i)
                    f[i] = (short)sm.pb[w][lg * 8 + i][16 * tt + lr];
                pf[tt] = f;
            }
            // A-frags of v^T + MFMA
            #pragma unroll
            for (int ht = 0; ht < 4; ++ht) {
                short8 vf = *(const short8*)&lvT[16 * ht + lr][sk * 32 + lg * 8];
                #pragma unroll
                for (int tt = 0; tt < 2; ++tt)
                    O[ht][tt] = MFMA16(vf, pf[tt], O[ht][tt]);
            }
        }
    }

    // ---- epilogue: out[b][t][h], contiguous float4 per lane ----
    float* ob = out + (size_t)b * (256 * 64);
    #pragma unroll
    for (int ht = 0; ht < 4; ++ht)
        #pragma unroll
        for (int tt = 0; tt < 2; ++tt) {
            const int t = 32 * w + 16 * tt + lr;
            *(f32x4*)&ob[t * 64 + 16 * ht + 4 * lg] = O[ht][tt];
        }
}

extern "C" void kernel_launch(void* const* d_in, const int* in_sizes, int n_in,
                              void* d_out, int out_size, void* d_ws, size_t ws_size,
                              hipStream_t stream) {
    const float* x  = (const float*)d_in[0];
    const float* Wq = (const float*)d_in[1];
    const float* Wk = (const float*)d_in[2];
    const float* Wv = (const float*)d_in[3];
    const float* dm = (const float*)d_in[4];
    float* outp     = (float*)d_out;
    attn_head_fused<<<dim3(512), dim3(512), 0, stream>>>(x, Wq, Wk, Wv, dm, outp);
}

// Round 3
// 68.886 us; speedup vs baseline: 1.0687x; 1.0687x over previous
//
#include <hip/hip_runtime.h>
#include <hip/hip_bf16.h>

typedef __attribute__((ext_vector_type(8))) short short8;
typedef __attribute__((ext_vector_type(4))) float f32x4;
typedef __attribute__((ext_vector_type(4))) unsigned short ushort4v;
typedef unsigned short u16;

#define MFMA32(a, b, c) __builtin_amdgcn_mfma_f32_16x16x32_bf16((a), (b), (c), 0, 0, 0)

__device__ __forceinline__ u16 f2bf(float f) {
    union { float f; unsigned int u; } v; v.f = f;
    unsigned int r = v.u + 0x7FFFu + ((v.u >> 16) & 1u);   // RNE to bf16
    return (u16)(r >> 16);
}

// One workgroup per batch. 8 waves. Balanced causal tiling:
// wave w owns 16-row t-tiles {w, 15-w} -> (w+1)+(16-w) = 17 s-tiles each, uniform.
// PV runs in 32-wide s-chunks: ceil((w+1)/2)+ceil((16-w)/2) = 9 chunks for every w.
__global__ __launch_bounds__(512, 2)
void attn_head_fused(const float* __restrict__ x,
                     const float* __restrict__ Wq,
                     const float* __restrict__ Wk,
                     const float* __restrict__ Wv,
                     const float* __restrict__ dmask,
                     float* __restrict__ out)
{
    // strides: multiples of 8 u16 keep b128 alignment; 264/72 give uniform bank spread
    __shared__ u16 lq[256][72];      // q  [t][h]
    __shared__ u16 lk[256][72];      // k  [s][h]
    __shared__ u16 lvT[64][264];     // v^T [h][s]
    __shared__ union {
        u16 wt[64][264];             // W^T [n][c]  (projection phase)
        u16 pb[8][16][40];           // per-wave P^T stored t-major [t_loc][s_loc]
    } sm;

    const int b   = blockIdx.x;
    const int tid = threadIdx.x;
    const int w   = tid >> 6;
    const int l   = tid & 63;
    const int lr  = l & 15;
    const int lg  = l >> 4;

    const int TbA  = 16 * w;          // t-tile A base
    const int TbB  = 16 * (15 - w);   // t-tile B base
    const int nst0 = w + 1;           // causal s-tiles for tile A
    const int nst1 = 16 - w;          // causal s-tiles for tile B (>= nst0)

    const float* xb = x + (size_t)b * (256 * 256);

    // ---- Phase 0: x A-fragments for the wave's two 16-row tiles (reused 3x) ----
    // A-frag (16x16x32): row = lr, k = ks*32 + lg*8 + [0..7]
    short8 af[2][8];
    #pragma unroll
    for (int ti = 0; ti < 2; ++ti) {
        const int Tb = ti ? TbB : TbA;
        const float* xr = xb + (size_t)(Tb + lr) * 256 + lg * 8;
        #pragma unroll
        for (int ks = 0; ks < 8; ++ks) {
            f32x4 a0 = *(const f32x4*)(xr + ks * 32);
            f32x4 a1 = *(const f32x4*)(xr + ks * 32 + 4);
            short8 f;
            f[0] = (short)f2bf(a0[0]); f[1] = (short)f2bf(a0[1]);
            f[2] = (short)f2bf(a0[2]); f[3] = (short)f2bf(a0[3]);
            f[4] = (short)f2bf(a1[0]); f[5] = (short)f2bf(a1[1]);
            f[6] = (short)f2bf(a1[2]); f[7] = (short)f2bf(a1[3]);
            af[ti][ks] = f;
        }
    }

    // ---- Phase 1: projections q, k, v ----
    const float* Ws[3] = {Wq, Wk, Wv};
    #pragma unroll
    for (int m = 0; m < 3; ++m) {
        const float* Wm = Ws[m];
        // stage W^T: lane l owns LDS row n=l; wave w owns c-chunks c0=8(w+8i).
        // Global reads: 64 consecutive dwords per instr (fully coalesced).
        // LDS write: b128 at row stride 132 dw (~4 mod 32) -> uniform 8 dw/bank (min).
        #pragma unroll
        for (int i = 0; i < 4; ++i) {
            const int c0 = 8 * (w + 8 * i);
            short8 wv;
            #pragma unroll
            for (int j = 0; j < 8; ++j)
                wv[j] = (short)f2bf(Wm[(size_t)(c0 + j) * 64 + l]);
            *(short8*)&sm.wt[l][c0] = wv;
        }
        __syncthreads();

        f32x4 acc[2][4];
        #pragma unroll
        for (int ti = 0; ti < 2; ++ti)
            #pragma unroll
            for (int nj = 0; nj < 4; ++nj)
                acc[ti][nj] = (f32x4){0.f, 0.f, 0.f, 0.f};

        #pragma unroll
        for (int ks = 0; ks < 8; ++ks) {
            #pragma unroll
            for (int nj = 0; nj < 4; ++nj) {
                short8 bf = *(const short8*)&sm.wt[16 * nj + lr][ks * 32 + lg * 8];
                #pragma unroll
                for (int ti = 0; ti < 2; ++ti)
                    acc[ti][nj] = MFMA32(af[ti][ks], bf, acc[ti][nj]);
            }
        }

        // C/D: col = lr, row = lg*4 + j (within 16x16 tile)
        if (m == 0 || m == 1) {
            u16 (*dst)[72] = (m == 0) ? lq : lk;
            #pragma unroll
            for (int ti = 0; ti < 2; ++ti) {
                const int t0 = (ti ? TbB : TbA) + 4 * lg;
                #pragma unroll
                for (int nj = 0; nj < 4; ++nj) {
                    const int n = 16 * nj + lr;
                    #pragma unroll
                    for (int j = 0; j < 4; ++j)
                        dst[t0 + j][n] = f2bf(acc[ti][nj][j]);
                }
            }
        } else {
            // v stored transposed: lvT[h][s]; 4 consecutive s -> one b64 write
            #pragma unroll
            for (int ti = 0; ti < 2; ++ti) {
                const int s0 = (ti ? TbB : TbA) + 4 * lg;
                #pragma unroll
                for (int nj = 0; nj < 4; ++nj) {
                    const int n = 16 * nj + lr;
                    ushort4v pk;
                    pk[0] = f2bf(acc[ti][nj][0]);
                    pk[1] = f2bf(acc[ti][nj][1]);
                    pk[2] = f2bf(acc[ti][nj][2]);
                    pk[3] = f2bf(acc[ti][nj][3]);
                    *(ushort4v*)&lvT[n][s0] = pk;
                }
            }
        }
        __syncthreads();
    }

    // ---- Phase 2: QK^T for the wave's two tiles ----
    short8 qf[2][2];
    #pragma unroll
    for (int ti = 0; ti < 2; ++ti) {
        const int Tb = ti ? TbB : TbA;
        #pragma unroll
        for (int ks = 0; ks < 2; ++ks)
            qf[ti][ks] = *(const short8*)&lq[Tb + lr][ks * 32 + lg * 8];
    }

    f32x4 S[16][2];   // [stile][ti], statically indexed, runtime-guarded
    #pragma unroll
    for (int st = 0; st < 16; ++st) {
        if (st < nst1) {   // nst1 >= nst0 always
            short8 kf0 = *(const short8*)&lk[16 * st + lr][lg * 8];
            short8 kf1 = *(const short8*)&lk[16 * st + lr][32 + lg * 8];
            if (st < nst0) {
                f32x4 a = (f32x4){0.f, 0.f, 0.f, 0.f};
                a = MFMA32(qf[0][0], kf0, a);
                a = MFMA32(qf[0][1], kf1, a);
                S[st][0] = a;
            }
            {
                f32x4 a = (f32x4){0.f, 0.f, 0.f, 0.f};
                a = MFMA32(qf[1][0], kf0, a);
                a = MFMA32(qf[1][1], kf1, a);
                S[st][1] = a;
            }
        }
    }

    // ---- softmax (rows t = Tb+4lg+j; cols s = 16st+lr) ----
    float mx[2][4], sum[2][4], rs[2][4];
    #pragma unroll
    for (int ti = 0; ti < 2; ++ti)
        #pragma unroll
        for (int j = 0; j < 4; ++j) { mx[ti][j] = -1e30f; sum[ti][j] = 0.f; }

    #pragma unroll
    for (int st = 0; st < 16; ++st) {
        const int s = 16 * st + lr;
        #pragma unroll
        for (int ti = 0; ti < 2; ++ti) {
            if (st < (ti ? nst1 : nst0)) {
                const int tb = (ti ? TbB : TbA) + 4 * lg;
                #pragma unroll
                for (int j = 0; j < 4; ++j) {
                    float Lv = (s <= tb + j) ? S[st][ti][j] * 0.125f : -1e30f;
                    S[st][ti][j] = Lv;
                    mx[ti][j] = fmaxf(mx[ti][j], Lv);
                }
            }
        }
    }
    #pragma unroll
    for (int d = 1; d < 16; d <<= 1)
        #pragma unroll
        for (int ti = 0; ti < 2; ++ti)
            #pragma unroll
            for (int j = 0; j < 4; ++j)
                mx[ti][j] = fmaxf(mx[ti][j], __shfl_xor(mx[ti][j], d, 64));

    #pragma unroll
    for (int st = 0; st < 16; ++st) {
        #pragma unroll
        for (int ti = 0; ti < 2; ++ti) {
            if (st < (ti ? nst1 : nst0)) {
                #pragma unroll
                for (int j = 0; j < 4; ++j) {
                    float p = exp2f((S[st][ti][j] - mx[ti][j]) * 1.44269504f);
                    S[st][ti][j] = p;
                    sum[ti][j] += p;
                }
            }
        }
    }

    // prefetch chunk-0 dropout masks for both tiles; latency hidden by shfl reduction
    const float* mb = dmask + (size_t)b * (256 * 256);
    float pm[2][2][4];   // [ti][subtile][j]
    #pragma unroll
    for (int ti = 0; ti < 2; ++ti) {
        const int tb  = (ti ? TbB : TbA) + 4 * lg;
        const int nst = ti ? nst1 : nst0;
        #pragma unroll
        for (int sl = 0; sl < 2; ++sl) {
            if (sl < nst) {
                #pragma unroll
                for (int j = 0; j < 4; ++j)
                    pm[ti][sl][j] = mb[(size_t)(tb + j) * 256 + 16 * sl + lr];
            }
        }
    }

    #pragma unroll
    for (int d = 1; d < 16; d <<= 1)
        #pragma unroll
        for (int ti = 0; ti < 2; ++ti)
            #pragma unroll
            for (int j = 0; j < 4; ++j)
                sum[ti][j] += __shfl_xor(sum[ti][j], d, 64);
    #pragma unroll
    for (int ti = 0; ti < 2; ++ti)
        #pragma unroll
        for (int j = 0; j < 4; ++j)
            rs[ti][j] = 1.33333333333f / sum[ti][j];   // (1/sum) * 1/(1-0.25)

    // ---- PV: out^T = v^T @ P^T, 32-wide s-chunks, masks prefetched one chunk ahead ----
    f32x4 O[4][2];
    #pragma unroll
    for (int ht = 0; ht < 4; ++ht)
        #pragma unroll
        for (int tt = 0; tt < 2; ++tt)
            O[ht][tt] = (f32x4){0.f, 0.f, 0.f, 0.f};

    #pragma unroll
    for (int ti = 0; ti < 2; ++ti) {
        const int nst = ti ? nst1 : nst0;
        const int tb  = (ti ? TbB : TbA) + 4 * lg;
        #pragma unroll
        for (int c = 0; c < 8; ++c) {
            if (2 * c < nst) {
                // prefetch next chunk's masks (fly during LDS transpose + MFMA)
                float nm[2][4] = {{0.f,0.f,0.f,0.f},{0.f,0.f,0.f,0.f}};
                #pragma unroll
                for (int sl = 0; sl < 2; ++sl) {
                    const int st = 2 * (c + 1) + sl;
                    if (st < nst) {
                        #pragma unroll
                        for (int j = 0; j < 4; ++j)
                            nm[sl][j] = mb[(size_t)(tb + j) * 256 + 16 * st + lr];
                    }
                }
                // P = softmax * dropout -> bf16 -> per-wave P^T (t-major), zero-pad tail
                #pragma unroll
                for (int sl = 0; sl < 2; ++sl) {
                    const int st = 2 * c + sl;
                    #pragma unroll
                    for (int j = 0; j < 4; ++j) {
                        float p = 0.f;
                        if (st < nst)
                            p = (pm[ti][sl][j] >= 0.25f) ? S[st][ti][j] * rs[ti][j] : 0.f;
                        sm.pb[w][4 * lg + j][16 * sl + lr] = f2bf(p);
                    }
                }
                asm volatile("s_waitcnt lgkmcnt(0)" ::: "memory");
                __builtin_amdgcn_sched_barrier(0);
                // B-frag of P^T: col t_loc = lr, k s_loc = lg*8 + [0..7] -> one b128
                short8 pf = *(const short8*)&sm.pb[w][lr][8 * lg];
                #pragma unroll
                for (int ht = 0; ht < 4; ++ht) {
                    short8 vf = *(const short8*)&lvT[16 * ht + lr][32 * c + 8 * lg];
                    O[ht][ti] = MFMA32(vf, pf, O[ht][ti]);
                }
                #pragma unroll
                for (int sl = 0; sl < 2; ++sl)
                    #pragma unroll
                    for (int j = 0; j < 4; ++j)
                        pm[ti][sl][j] = nm[sl][j];
            }
        }
    }

    // ---- epilogue: out[b][t][h], contiguous float4 per lane ----
    float* ob = out + (size_t)b * (256 * 64);
    #pragma unroll
    for (int ti = 0; ti < 2; ++ti) {
        const int t = (ti ? TbB : TbA) + lr;
        #pragma unroll
        for (int ht = 0; ht < 4; ++ht)
            *(f32x4*)&ob[t * 64 + 16 * ht + 4 * lg] = O[ht][ti];
    }
}

extern "C" void kernel_launch(void* const* d_in, const int* in_sizes, int n_in,
                              void* d_out, int out_size, void* d_ws, size_t ws_size,
                              hipStream_t stream) {
    const float* x  = (const float*)d_in[0];
    const float* Wq = (const float*)d_in[1];
    const float* Wk = (const float*)d_in[2];
    const float* Wv = (const float*)d_in[3];
    const float* dm = (const float*)d_in[4];
    float* outp     = (float*)d_out;
    attn_head_fused<<<dim3(512), dim3(512), 0, stream>>>(x, Wq, Wk, Wv, dm, outp);
}